// Round 2
// baseline (546.432 us; speedup 1.0000x reference)
//
#include <hip/hip_runtime.h>
#include <math.h>

typedef float f2 __attribute__((ext_vector_type(2)));
typedef float f2u __attribute__((ext_vector_type(2), aligned(4)));
typedef float f4 __attribute__((ext_vector_type(4)));

#define BN 8
#define CIN 3
#define HH 512
#define WW 512
#define KK 9
#define PATCH 27

// ws layout (floats):
//   [0,756)   : conv weights, row j (patch elem j = c*9 + kh*3 + kw), stride 28:
//               ws[j*28 + q] = w_off[ch(q)*27 + j]   (ch(q) invalid -> 0)
//               pair mapping ch(q): p=q>>1, h=q&1 ->
//                 p<9  : 2p+h          (offset channels, pairs (oy_k, ox_k))
//                 p>=9 : 18+2(p-9)+h   (mask channels, pairs (m0,m1)..(m8,pad))
//   [768,876) : contraction, ws[768 + k*12 + c*4 + o] = o<3 ? w_def[o*27+c*9+k] : 0
//   [880,908) : packed bias, ws[880 + q] = b_off[ch(q)]  (invalid -> 0)

__device__ __forceinline__ int pair_ch(int q) {
    const int p = q >> 1, hh = q & 1;
    return (p < 9) ? (2 * p + hh) : (18 + 2 * (p - 9) + hh);
}

__global__ void reorder_weights(const float* __restrict__ w_off,
                                const float* __restrict__ w_def,
                                const float* __restrict__ b_off,
                                float* __restrict__ ws)
{
    for (int idx = threadIdx.x; idx < 908; idx += blockDim.x) {
        float v = 0.0f;
        if (idx < 756) {
            const int j = idx / 28, q = idx % 28;
            const int ch = pair_ch(q);
            if (ch < PATCH) v = w_off[ch * PATCH + j];
        } else if (idx >= 768 && idx < 876) {
            const int r = idx - 768;
            const int k = r / 12, c = (r % 12) >> 2, o = r & 3;
            if (o < 3) v = w_def[o * PATCH + c * KK + k];
        } else if (idx >= 880) {
            const int q = idx - 880;
            const int ch = pair_ch(q);
            if (ch < PATCH) v = b_off[ch];
        }
        ws[idx] = v;
    }
}

__global__ __launch_bounds__(256, 4) void deform_fused_kernel(
    const float* __restrict__ x,
    const float* __restrict__ wsw,    // reordered weights/bias, uniform -> s_load
    const float* __restrict__ b_def,
    float* __restrict__ out)
{
    const int w = blockIdx.x * blockDim.x + threadIdx.x;
    const int h = blockIdx.y;
    const int b = blockIdx.z;

    const size_t plane = (size_t)HH * WW;
    const float* xb = x + (size_t)b * CIN * plane;

    // ---- 3x3x3 zero-padded patch, flat index = c*9 + t ----
    float patch[PATCH];
    #pragma unroll
    for (int c = 0; c < CIN; ++c) {
        const float* xp = xb + c * plane;
        #pragma unroll
        for (int t = 0; t < KK; ++t) {
            const int yy = h + t / 3 - 1;
            const int xx = w + t % 3 - 1;
            const bool in = (yy >= 0) & (yy < HH) & (xx >= 0) & (xx < WW);
            patch[c * KK + t] = in ? xp[yy * WW + xx] : 0.0f;
        }
    }

    // ---- conv pass 1: 9 offset-pair accumulators (oy_k, ox_k) ----
    f2 cvo[9];
    #pragma unroll
    for (int p = 0; p < 9; ++p) cvo[p] = *(const f2*)(wsw + 880 + 2 * p);

    #pragma unroll
    for (int j = 0; j < PATCH; ++j) {
        const f2 pp = { patch[j], patch[j] };
        const float* row = wsw + j * 28;   // uniform -> s_load
        #pragma unroll
        for (int p = 0; p < 9; ++p) {
            cvo[p] = __builtin_elementwise_fma(*(const f2*)(row + 2 * p), pp, cvo[p]);
        }
    }

    // ---- conv pass 2: 5 mask-logit-pair accumulators ----
    f2 cvm[5];
    #pragma unroll
    for (int p = 0; p < 5; ++p) cvm[p] = *(const f2*)(wsw + 880 + 18 + 2 * p);

    #pragma unroll
    for (int j = 0; j < PATCH; ++j) {
        const f2 pp = { patch[j], patch[j] };
        const float* row = wsw + j * 28 + 18;
        #pragma unroll
        for (int p = 0; p < 5; ++p) {
            cvm[p] = __builtin_elementwise_fma(*(const f2*)(row + 2 * p), pp, cvm[p]);
        }
    }

    f2 acc01 = { b_def[0], b_def[1] };
    float acc2 = b_def[2];

    // ---- tap loop: bilinear sample + contraction; fully unrolled (static idx) ----
    #pragma unroll
    for (int k = 0; k < KK; ++k) {
        const f2 oyx = cvo[k];                              // (oy_k, ox_k)
        const float om = (k & 1) ? cvm[k >> 1].y
                                 : cvm[k >> 1].x;           // mask logit
        const float m = 1.0f / (1.0f + __expf(-om));

        const float py = (float)h + (float)(k / 3 - 1) + oyx.x;
        const float px = (float)w + (float)(k % 3 - 1) + oyx.y;
        const float y0f = floorf(py);
        const float x0f = floorf(px);
        const float dy = py - y0f;
        const float dx = px - x0f;
        const int y0 = (int)y0f;
        const int x0 = (int)x0f;

        const f2 dxp = { 1.0f - dx, dx };
        const f2 wT = dxp * (1.0f - dy);   // (w00, w01)
        const f2 wB = dxp * dy;            // (w10, w11)

        const int interior = (y0 >= 0) & (y0 + 1 < HH) & (x0 >= 0) & (x0 + 1 < WW);
        const float* blkc = wsw + 768 + k * 12;

        if (__all(interior)) {
            const int idx = y0 * WW + x0;
            #pragma unroll
            for (int c = 0; c < CIN; ++c) {
                const float* xp = xb + c * plane + idx;
                const f2 vT = *(const f2u*)(xp);
                const f2 vB = *(const f2u*)(xp + WW);
                f2 s = vT * wT;
                s = __builtin_elementwise_fma(vB, wB, s);
                const float val = (s.x + s.y) * m;
                const f4 wq = *(const f4*)(blkc + 4 * c);
                const f2 w01 = { wq.x, wq.y };
                const f2 vv = { val, val };
                acc01 = __builtin_elementwise_fma(w01, vv, acc01);
                acc2 = fmaf(wq.z, val, acc2);
            }
        } else {
            const bool vy0 = (y0 >= 0)     & (y0 < HH);
            const bool vy1 = (y0 + 1 >= 0) & (y0 + 1 < HH);
            const bool vx0 = (x0 >= 0)     & (x0 < WW);
            const bool vx1 = (x0 + 1 >= 0) & (x0 + 1 < WW);

            const int yc0 = min(max(y0, 0), HH - 1);
            const int yc1 = min(max(y0 + 1, 0), HH - 1);
            const int xc0 = min(max(x0, 0), WW - 1);
            const int xc1 = min(max(x0 + 1, 0), WW - 1);

            #pragma unroll
            for (int c = 0; c < CIN; ++c) {
                const float* xp = xb + c * plane;
                const float v00 = (vy0 & vx0) ? xp[yc0 * WW + xc0] : 0.0f;
                const float v01 = (vy0 & vx1) ? xp[yc0 * WW + xc1] : 0.0f;
                const float v10 = (vy1 & vx0) ? xp[yc1 * WW + xc0] : 0.0f;
                const float v11 = (vy1 & vx1) ? xp[yc1 * WW + xc1] : 0.0f;

                const float val =
                    (v00 * wT.x + v01 * wT.y + v10 * wB.x + v11 * wB.y) * m;
                const f4 wq = *(const f4*)(blkc + 4 * c);
                const f2 w01 = { wq.x, wq.y };
                const f2 vv = { val, val };
                acc01 = __builtin_elementwise_fma(w01, vv, acc01);
                acc2 = fmaf(wq.z, val, acc2);
            }
        }
    }

    const size_t base = (size_t)b * (CIN * plane) + (size_t)h * WW + w;
    out[base]             = acc01.x;
    out[base + plane]     = acc01.y;
    out[base + 2 * plane] = acc2;
}

extern "C" void kernel_launch(void* const* d_in, const int* in_sizes, int n_in,
                              void* d_out, int out_size, void* d_ws, size_t ws_size,
                              hipStream_t stream) {
    const float* x     = (const float*)d_in[0];
    const float* w_off = (const float*)d_in[1];
    const float* b_off = (const float*)d_in[2];
    const float* w_def = (const float*)d_in[3];
    const float* b_def = (const float*)d_in[4];
    float* out = (float*)d_out;
    float* wsw = (float*)d_ws;   // 908 floats of reordered weights/bias

    reorder_weights<<<1, 256, 0, stream>>>(w_off, w_def, b_off, wsw);

    dim3 block(256, 1, 1);
    dim3 grid(WW / 256, HH, BN);  // (2, 512, 8)
    deform_fused_kernel<<<grid, block, 0, stream>>>(x, wsw, b_def, out);
}

// Round 3
// 460.936 us; speedup vs baseline: 1.1855x; 1.1855x over previous
//
#include <hip/hip_runtime.h>
#include <math.h>

typedef float f2 __attribute__((ext_vector_type(2)));
typedef float f2u __attribute__((ext_vector_type(2), aligned(4)));
typedef float f4 __attribute__((ext_vector_type(4)));

#define BN 8
#define CIN 3
#define HH 512
#define WW 512
#define KK 9
#define PATCH 27

// ws layout (floats):
//   [0,756)   : conv weights, row j (patch elem j = c*9 + kh*3 + kw), stride 28:
//               ws[j*28 + q] = w_off[ch(q)*27 + j]   (ch(q) invalid -> 0)
//               pair mapping ch(q): p=q>>1, h=q&1 ->
//                 p<9  : 2p+h          (offset channels, pairs (oy_k, ox_k))
//                 p>=9 : 18+2(p-9)+h   (mask channels, pairs (m0,m1)..(m8,pad))
//   [768,876) : contraction, ws[768 + k*12 + c*4 + o] = o<3 ? w_def[o*27+c*9+k] : 0
//   [880,908) : packed bias, ws[880 + q] = b_off[ch(q)]  (invalid -> 0)

__device__ __forceinline__ int pair_ch(int q) {
    const int p = q >> 1, hh = q & 1;
    return (p < 9) ? (2 * p + hh) : (18 + 2 * (p - 9) + hh);
}

__global__ void reorder_weights(const float* __restrict__ w_off,
                                const float* __restrict__ w_def,
                                const float* __restrict__ b_off,
                                float* __restrict__ ws)
{
    for (int idx = threadIdx.x; idx < 908; idx += blockDim.x) {
        float v = 0.0f;
        if (idx < 756) {
            const int j = idx / 28, q = idx % 28;
            const int ch = pair_ch(q);
            if (ch < PATCH) v = w_off[ch * PATCH + j];
        } else if (idx >= 768 && idx < 876) {
            const int r = idx - 768;
            const int k = r / 12, c = (r % 12) >> 2, o = r & 3;
            if (o < 3) v = w_def[o * PATCH + c * KK + k];
        } else if (idx >= 880) {
            const int q = idx - 880;
            const int ch = pair_ch(q);
            if (ch < PATCH) v = b_off[ch];
        }
        ws[idx] = v;
    }
}

// ---- one conv step: patch elem J feeds all 14 named accumulators ----
#define CSTEP(J) do {                                                   \
    const f2 pp_ = { patch[J], patch[J] };                              \
    const f2* rw_ = (const f2*)(wsw + (J) * 28);                        \
    c0  = __builtin_elementwise_fma(rw_[0],  pp_, c0 );                 \
    c1  = __builtin_elementwise_fma(rw_[1],  pp_, c1 );                 \
    c2  = __builtin_elementwise_fma(rw_[2],  pp_, c2 );                 \
    c3  = __builtin_elementwise_fma(rw_[3],  pp_, c3 );                 \
    c4  = __builtin_elementwise_fma(rw_[4],  pp_, c4 );                 \
    c5  = __builtin_elementwise_fma(rw_[5],  pp_, c5 );                 \
    c6  = __builtin_elementwise_fma(rw_[6],  pp_, c6 );                 \
    c7  = __builtin_elementwise_fma(rw_[7],  pp_, c7 );                 \
    c8  = __builtin_elementwise_fma(rw_[8],  pp_, c8 );                 \
    c9  = __builtin_elementwise_fma(rw_[9],  pp_, c9 );                 \
    c10 = __builtin_elementwise_fma(rw_[10], pp_, c10);                 \
    c11 = __builtin_elementwise_fma(rw_[11], pp_, c11);                 \
    c12 = __builtin_elementwise_fma(rw_[12], pp_, c12);                 \
    c13 = __builtin_elementwise_fma(rw_[13], pp_, c13);                 \
} while (0)

// ---- one deformable tap: bilinear sample + contraction (baseline-proven body) ----
#define TAP(K, OYX, OM) do {                                            \
    const float om_ = (OM);                                             \
    const float m_ = 1.0f / (1.0f + __expf(-om_));                      \
    const float py_ = (float)h + (float)((K) / 3 - 1) + (OYX).x;        \
    const float px_ = (float)w + (float)((K) % 3 - 1) + (OYX).y;        \
    const float y0f_ = floorf(py_);                                     \
    const float x0f_ = floorf(px_);                                     \
    const float dy_ = py_ - y0f_;                                       \
    const float dx_ = px_ - x0f_;                                       \
    const int y0_ = (int)y0f_;                                          \
    const int x0_ = (int)x0f_;                                          \
    const f2 dxp_ = { 1.0f - dx_, dx_ };                                \
    const f2 wT_ = dxp_ * (1.0f - dy_);                                 \
    const f2 wB_ = dxp_ * dy_;                                          \
    const int interior_ =                                               \
        (y0_ >= 0) & (y0_ + 1 < HH) & (x0_ >= 0) & (x0_ + 1 < WW);      \
    const float* blkc_ = wsw + 768 + (K) * 12;                          \
    if (__all(interior_)) {                                             \
        const int idx_ = y0_ * WW + x0_;                                \
        _Pragma("unroll")                                               \
        for (int c = 0; c < CIN; ++c) {                                 \
            const float* xp_ = xb + c * plane + idx_;                   \
            const f2 vT_ = *(const f2u*)(xp_);                          \
            const f2 vB_ = *(const f2u*)(xp_ + WW);                     \
            f2 s_ = vT_ * wT_;                                          \
            s_ = __builtin_elementwise_fma(vB_, wB_, s_);               \
            const float val_ = (s_.x + s_.y) * m_;                      \
            const f4 wq_ = *(const f4*)(blkc_ + 4 * c);                 \
            const f2 w01_ = { wq_.x, wq_.y };                           \
            const f2 vv_ = { val_, val_ };                              \
            acc01 = __builtin_elementwise_fma(w01_, vv_, acc01);        \
            acc2 = fmaf(wq_.z, val_, acc2);                             \
        }                                                               \
    } else {                                                            \
        const bool vy0_ = (y0_ >= 0)     & (y0_ < HH);                  \
        const bool vy1_ = (y0_ + 1 >= 0) & (y0_ + 1 < HH);              \
        const bool vx0_ = (x0_ >= 0)     & (x0_ < WW);                  \
        const bool vx1_ = (x0_ + 1 >= 0) & (x0_ + 1 < WW);              \
        const int yc0_ = min(max(y0_, 0), HH - 1);                      \
        const int yc1_ = min(max(y0_ + 1, 0), HH - 1);                  \
        const int xc0_ = min(max(x0_, 0), WW - 1);                      \
        const int xc1_ = min(max(x0_ + 1, 0), WW - 1);                  \
        _Pragma("unroll")                                               \
        for (int c = 0; c < CIN; ++c) {                                 \
            const float* xp_ = xb + c * plane;                          \
            const float v00_ = (vy0_ & vx0_) ? xp_[yc0_ * WW + xc0_] : 0.0f; \
            const float v01_ = (vy0_ & vx1_) ? xp_[yc0_ * WW + xc1_] : 0.0f; \
            const float v10_ = (vy1_ & vx0_) ? xp_[yc1_ * WW + xc0_] : 0.0f; \
            const float v11_ = (vy1_ & vx1_) ? xp_[yc1_ * WW + xc1_] : 0.0f; \
            const float val_ =                                          \
                (v00_ * wT_.x + v01_ * wT_.y + v10_ * wB_.x + v11_ * wB_.y) * m_; \
            const f4 wq_ = *(const f4*)(blkc_ + 4 * c);                 \
            const f2 w01_ = { wq_.x, wq_.y };                           \
            const f2 vv_ = { val_, val_ };                              \
            acc01 = __builtin_elementwise_fma(w01_, vv_, acc01);        \
            acc2 = fmaf(wq_.z, val_, acc2);                             \
        }                                                               \
    }                                                                   \
} while (0)

__global__ __launch_bounds__(256) void deform_fused_kernel(
    const float* __restrict__ x,
    const float* __restrict__ wsw,    // reordered weights/bias, uniform -> s_load
    const float* __restrict__ b_def,
    float* __restrict__ out)
{
    const int w = blockIdx.x * blockDim.x + threadIdx.x;
    const int h = blockIdx.y;
    const int b = blockIdx.z;

    const size_t plane = (size_t)HH * WW;
    const float* xb = x + (size_t)b * CIN * plane;

    // ---- 3x3x3 zero-padded patch, flat index = c*9 + t (baseline-proven) ----
    float patch[PATCH];
    #pragma unroll
    for (int c = 0; c < CIN; ++c) {
        const float* xp = xb + c * plane;
        #pragma unroll
        for (int t = 0; t < KK; ++t) {
            const int yy = h + t / 3 - 1;
            const int xx = w + t % 3 - 1;
            const bool in = (yy >= 0) & (yy < HH) & (xx >= 0) & (xx < WW);
            patch[c * KK + t] = in ? xp[yy * WW + xx] : 0.0f;
        }
    }

    // ---- one-pass 27->28ch conv: 14 NAMED f2 accumulators, macro-unrolled ----
    f2 c0  = *(const f2*)(wsw + 880 +  0);
    f2 c1  = *(const f2*)(wsw + 880 +  2);
    f2 c2  = *(const f2*)(wsw + 880 +  4);
    f2 c3  = *(const f2*)(wsw + 880 +  6);
    f2 c4  = *(const f2*)(wsw + 880 +  8);
    f2 c5  = *(const f2*)(wsw + 880 + 10);
    f2 c6  = *(const f2*)(wsw + 880 + 12);
    f2 c7  = *(const f2*)(wsw + 880 + 14);
    f2 c8  = *(const f2*)(wsw + 880 + 16);
    f2 c9  = *(const f2*)(wsw + 880 + 18);
    f2 c10 = *(const f2*)(wsw + 880 + 20);
    f2 c11 = *(const f2*)(wsw + 880 + 22);
    f2 c12 = *(const f2*)(wsw + 880 + 24);
    f2 c13 = *(const f2*)(wsw + 880 + 26);

    CSTEP(0);  CSTEP(1);  CSTEP(2);  CSTEP(3);  CSTEP(4);  CSTEP(5);
    CSTEP(6);  CSTEP(7);  CSTEP(8);  CSTEP(9);  CSTEP(10); CSTEP(11);
    CSTEP(12); CSTEP(13); CSTEP(14); CSTEP(15); CSTEP(16); CSTEP(17);
    CSTEP(18); CSTEP(19); CSTEP(20); CSTEP(21); CSTEP(22); CSTEP(23);
    CSTEP(24); CSTEP(25); CSTEP(26);

    f2 acc01 = { b_def[0], b_def[1] };
    float acc2 = b_def[2];

    // ---- 9 taps, explicit static invocations (c0..c8 = (oy,ox); c9..c13 = mask pairs)
    TAP(0, c0, c9.x);
    TAP(1, c1, c9.y);
    TAP(2, c2, c10.x);
    TAP(3, c3, c10.y);
    TAP(4, c4, c11.x);
    TAP(5, c5, c11.y);
    TAP(6, c6, c12.x);
    TAP(7, c7, c12.y);
    TAP(8, c8, c13.x);

    const size_t base = (size_t)b * (CIN * plane) + (size_t)h * WW + w;
    out[base]             = acc01.x;
    out[base + plane]     = acc01.y;
    out[base + 2 * plane] = acc2;
}

extern "C" void kernel_launch(void* const* d_in, const int* in_sizes, int n_in,
                              void* d_out, int out_size, void* d_ws, size_t ws_size,
                              hipStream_t stream) {
    const float* x     = (const float*)d_in[0];
    const float* w_off = (const float*)d_in[1];
    const float* b_off = (const float*)d_in[2];
    const float* w_def = (const float*)d_in[3];
    const float* b_def = (const float*)d_in[4];
    float* out = (float*)d_out;
    float* wsw = (float*)d_ws;   // 908 floats of reordered weights/bias

    reorder_weights<<<1, 256, 0, stream>>>(w_off, w_def, b_off, wsw);

    dim3 block(256, 1, 1);
    dim3 grid(WW / 256, HH, BN);  // (2, 512, 8)
    deform_fused_kernel<<<grid, block, 0, stream>>>(x, wsw, b_def, out);
}

// Round 4
// 184.496 us; speedup vs baseline: 2.9617x; 2.4984x over previous
//
#include <hip/hip_runtime.h>
#include <math.h>

typedef float f2 __attribute__((ext_vector_type(2)));
typedef float f2u __attribute__((ext_vector_type(2), aligned(4)));
typedef float f4 __attribute__((ext_vector_type(4)));

#define BN 8
#define CIN 3
#define HH 512
#define WW 512
#define KK 9
#define PATCH 27
#define TAPBLK 96  // 56 (wy,wx) pair floats | 28 wm | 12 contraction = 96 = 6x dwordx16

// ws layout, tap k block of 96 floats (base 64B-aligned):
//  r in [0,56):  pair q=r>>1, half=r&1 -> w_off[(2k+half)*27+q], q>=27 -> 0
//  r in [56,84): i=r-56 -> w_off[(18+k)*27+i], i>=27 -> 0
//  r in [84,96): j=r-84, c=j>>2, o=j&3 -> o<3 ? w_def[o*27 + c*9 + k] : 0
__global__ void reorder_weights(const float* __restrict__ w_off,
                                const float* __restrict__ w_def,
                                float* __restrict__ ws)
{
    for (int idx = threadIdx.x; idx < KK * TAPBLK; idx += blockDim.x) {
        const int k = idx / TAPBLK;
        const int r = idx % TAPBLK;
        float v = 0.0f;
        if (r < 56) {
            const int q = r >> 1, half = r & 1;
            if (q < PATCH) v = w_off[(2 * k + half) * PATCH + q];
        } else if (r < 84) {
            const int i = r - 56;
            if (i < PATCH) v = w_off[(18 + k) * PATCH + i];
        } else {
            const int j = r - 84;
            const int c = j >> 2, o = j & 3;
            if (o < 3) v = w_def[o * PATCH + c * KK + k];
        }
        ws[idx] = v;
    }
}

__global__ __launch_bounds__(256) void deform_fused_kernel(
    const float* __restrict__ x,
    const float* __restrict__ wsw,    // reordered weights, 864 floats (uniform -> SMEM)
    const float* __restrict__ b_off,
    const float* __restrict__ b_def,
    float* __restrict__ out)
{
    const int w = blockIdx.x * blockDim.x + threadIdx.x;
    const int h = blockIdx.y;
    const int b = blockIdx.z;

    const size_t plane = (size_t)HH * WW;
    const float* xb = x + (size_t)b * CIN * plane;

    // ---- 3x3x3 zero-padded patch, flat index = c*9 + t; pad elem 27 = 0 ----
    float patch[28];
    patch[27] = 0.0f;
    #pragma unroll
    for (int c = 0; c < CIN; ++c) {
        const float* xp = xb + c * plane;
        #pragma unroll
        for (int t = 0; t < KK; ++t) {
            const int yy = h + t / 3 - 1;
            const int xx = w + t % 3 - 1;
            const bool in = (yy >= 0) & (yy < HH) & (xx >= 0) & (xx < WW);
            patch[c * KK + t] = in ? xp[yy * WW + xx] : 0.0f;
        }
    }

    f2 acc01 = { b_def[0], b_def[1] };
    float acc2 = b_def[2];

    #pragma unroll 1
    for (int k = 0; k < KK; ++k) {
        const float* blk = wsw + k * TAPBLK;   // uniform address -> s_load

        // ---- per-tap conv: 2 parity-split chains per accumulator (ILP fix) ----
        f2 oyxA = { b_off[2 * k], b_off[2 * k + 1] };
        f2 oyxB = { 0.0f, 0.0f };
        float omA = b_off[18 + k];
        float omB = 0.0f;

        #pragma unroll
        for (int j = 0; j < 14; ++j) {
            const f4 wq = *(const f4*)(blk + 4 * j);
            const float p0 = patch[2 * j];
            const float p1 = patch[2 * j + 1];
            const f2 w0 = { wq.x, wq.y };
            const f2 w1 = { wq.z, wq.w };
            const f2 pp0 = { p0, p0 };
            const f2 pp1 = { p1, p1 };
            if (j & 1) {
                oyxB = __builtin_elementwise_fma(w0, pp0, oyxB);
                oyxB = __builtin_elementwise_fma(w1, pp1, oyxB);
            } else {
                oyxA = __builtin_elementwise_fma(w0, pp0, oyxA);
                oyxA = __builtin_elementwise_fma(w1, pp1, oyxA);
            }
        }
        #pragma unroll
        for (int j = 0; j < 7; ++j) {
            const f4 wm4 = *(const f4*)(blk + 56 + 4 * j);
            if (j & 1) {
                omB = fmaf(wm4.x, patch[4 * j],     omB);
                omB = fmaf(wm4.y, patch[4 * j + 1], omB);
                omB = fmaf(wm4.z, patch[4 * j + 2], omB);
                omB = fmaf(wm4.w, patch[4 * j + 3], omB);
            } else {
                omA = fmaf(wm4.x, patch[4 * j],     omA);
                omA = fmaf(wm4.y, patch[4 * j + 1], omA);
                omA = fmaf(wm4.z, patch[4 * j + 2], omA);
                omA = fmaf(wm4.w, patch[4 * j + 3], omA);
            }
        }

        const f2 oyx = oyxA + oyxB;
        const float om = omA + omB;

        const float m = 1.0f / (1.0f + __expf(-om));

        const float py = (float)h + (float)(k / 3 - 1) + oyx.x;
        const float px = (float)w + (float)(k % 3 - 1) + oyx.y;
        const float y0f = floorf(py);
        const float x0f = floorf(px);
        const float dy = py - y0f;
        const float dx = px - x0f;
        const int y0 = (int)y0f;
        const int x0 = (int)x0f;

        const f2 dxp = { 1.0f - dx, dx };
        const f2 wT = dxp * (1.0f - dy);   // (w00, w01)
        const f2 wB = dxp * dy;            // (w10, w11)

        const int interior = (y0 >= 0) & (y0 + 1 < HH) & (x0 >= 0) & (x0 + 1 < WW);

        if (__all(interior)) {
            const int idx = y0 * WW + x0;
            #pragma unroll
            for (int c = 0; c < CIN; ++c) {
                const float* xp = xb + c * plane + idx;
                const f2 vT = *(const f2u*)(xp);
                const f2 vB = *(const f2u*)(xp + WW);
                f2 s = vT * wT;
                s = __builtin_elementwise_fma(vB, wB, s);
                const float val = (s.x + s.y) * m;
                const f4 wq = *(const f4*)(blk + 84 + 4 * c);
                const f2 w01 = { wq.x, wq.y };
                const f2 vv = { val, val };
                acc01 = __builtin_elementwise_fma(w01, vv, acc01);
                acc2 = fmaf(wq.z, val, acc2);
            }
        } else {
            const bool vy0 = (y0 >= 0)     & (y0 < HH);
            const bool vy1 = (y0 + 1 >= 0) & (y0 + 1 < HH);
            const bool vx0 = (x0 >= 0)     & (x0 < WW);
            const bool vx1 = (x0 + 1 >= 0) & (x0 + 1 < WW);

            const int yc0 = min(max(y0, 0), HH - 1);
            const int yc1 = min(max(y0 + 1, 0), HH - 1);
            const int xc0 = min(max(x0, 0), WW - 1);
            const int xc1 = min(max(x0 + 1, 0), WW - 1);

            #pragma unroll
            for (int c = 0; c < CIN; ++c) {
                const float* xp = xb + c * plane;
                const float v00 = (vy0 & vx0) ? xp[yc0 * WW + xc0] : 0.0f;
                const float v01 = (vy0 & vx1) ? xp[yc0 * WW + xc1] : 0.0f;
                const float v10 = (vy1 & vx0) ? xp[yc1 * WW + xc0] : 0.0f;
                const float v11 = (vy1 & vx1) ? xp[yc1 * WW + xc1] : 0.0f;

                const float val =
                    (v00 * wT.x + v01 * wT.y + v10 * wB.x + v11 * wB.y) * m;
                const f4 wq = *(const f4*)(blk + 84 + 4 * c);
                const f2 w01 = { wq.x, wq.y };
                const f2 vv = { val, val };
                acc01 = __builtin_elementwise_fma(w01, vv, acc01);
                acc2 = fmaf(wq.z, val, acc2);
            }
        }
    }

    const size_t base = (size_t)b * (CIN * plane) + (size_t)h * WW + w;
    out[base]             = acc01.x;
    out[base + plane]     = acc01.y;
    out[base + 2 * plane] = acc2;
}

extern "C" void kernel_launch(void* const* d_in, const int* in_sizes, int n_in,
                              void* d_out, int out_size, void* d_ws, size_t ws_size,
                              hipStream_t stream) {
    const float* x     = (const float*)d_in[0];
    const float* w_off = (const float*)d_in[1];
    const float* b_off = (const float*)d_in[2];
    const float* w_def = (const float*)d_in[3];
    const float* b_def = (const float*)d_in[4];
    float* out = (float*)d_out;
    float* wsw = (float*)d_ws;   // 864 floats of reordered weights

    reorder_weights<<<1, 256, 0, stream>>>(w_off, w_def, wsw);

    dim3 block(256, 1, 1);
    dim3 grid(WW / 256, HH, BN);  // (2, 512, 8)
    deform_fused_kernel<<<grid, block, 0, stream>>>(x, wsw, b_off, b_def, out);
}

// Round 5
// 182.420 us; speedup vs baseline: 2.9955x; 1.0114x over previous
//
#include <hip/hip_runtime.h>
#include <math.h>

typedef float f2 __attribute__((ext_vector_type(2)));
typedef float f2u __attribute__((ext_vector_type(2), aligned(4)));
typedef float f4 __attribute__((ext_vector_type(4)));

#define BN 8
#define CIN 3
#define HH 512
#define WW 512
#define KK 9
#define PATCH 27
#define TAPBLK 96  // 56 (wy,wx) pair floats | 28 wm | 12 contraction = 96 = 6x dwordx16

// ws layout, tap k block of 96 floats (base 64B-aligned):
//  r in [0,56):  pair q=r>>1, half=r&1 -> w_off[(2k+half)*27+q], q>=27 -> 0
//  r in [56,84): i=r-56 -> w_off[(18+k)*27+i], i>=27 -> 0
//  r in [84,96): j=r-84, c=j>>2, o=j&3 -> o<3 ? w_def[o*27 + c*9 + k] : 0
__global__ void reorder_weights(const float* __restrict__ w_off,
                                const float* __restrict__ w_def,
                                float* __restrict__ ws)
{
    for (int idx = threadIdx.x; idx < KK * TAPBLK; idx += blockDim.x) {
        const int k = idx / TAPBLK;
        const int r = idx % TAPBLK;
        float v = 0.0f;
        if (r < 56) {
            const int q = r >> 1, half = r & 1;
            if (q < PATCH) v = w_off[(2 * k + half) * PATCH + q];
        } else if (r < 84) {
            const int i = r - 56;
            if (i < PATCH) v = w_off[(18 + k) * PATCH + i];
        } else {
            const int j = r - 84;
            const int c = j >> 2, o = j & 3;
            if (o < 3) v = w_def[o * PATCH + c * KK + k];
        }
        ws[idx] = v;
    }
}

__global__ __launch_bounds__(256) void deform_fused_kernel(
    const float* __restrict__ x,
    const float* __restrict__ wsw,    // reordered weights, 864 floats (uniform -> SMEM)
    const float* __restrict__ b_off,
    const float* __restrict__ b_def,
    float* __restrict__ out)
{
    const int w = blockIdx.x * blockDim.x + threadIdx.x;
    const int h = blockIdx.y;
    const int b = blockIdx.z;

    const size_t plane = (size_t)HH * WW;
    const float* xb = x + (size_t)b * CIN * plane;

    // ---- 3x3x3 zero-padded patch, flat index = c*9 + t; pad elem 27 = 0 ----
    float patch[28];
    patch[27] = 0.0f;
    #pragma unroll
    for (int c = 0; c < CIN; ++c) {
        const float* xp = xb + c * plane;
        #pragma unroll
        for (int t = 0; t < KK; ++t) {
            const int yy = h + t / 3 - 1;
            const int xx = w + t % 3 - 1;
            const bool in = (yy >= 0) & (yy < HH) & (xx >= 0) & (xx < WW);
            patch[c * KK + t] = in ? xp[yy * WW + xx] : 0.0f;
        }
    }

    const float hf = (float)h;
    const float wf = (float)w;

    f2 acc01 = { b_def[0], b_def[1] };
    float acc2 = b_def[2];

    // ---- prologue: conv for tap 0 (proven per-tap structure) ----
    f2 oyx;
    float om;
    {
        const float* blk = wsw;   // tap 0
        f2 a = { b_off[0], b_off[1] };
        float s = b_off[18];
        #pragma unroll
        for (int j = 0; j < 14; ++j) {
            const f4 wq = *(const f4*)(blk + 4 * j);
            const float p0 = patch[2 * j];
            const float p1 = patch[2 * j + 1];
            const f2 w0 = { wq.x, wq.y };
            const f2 w1 = { wq.z, wq.w };
            const f2 pp0 = { p0, p0 };
            const f2 pp1 = { p1, p1 };
            a = __builtin_elementwise_fma(w0, pp0, a);
            a = __builtin_elementwise_fma(w1, pp1, a);
        }
        #pragma unroll
        for (int j = 0; j < 7; ++j) {
            const f4 wm4 = *(const f4*)(blk + 56 + 4 * j);
            s = fmaf(wm4.x, patch[4 * j],     s);
            s = fmaf(wm4.y, patch[4 * j + 1], s);
            s = fmaf(wm4.z, patch[4 * j + 2], s);
            s = fmaf(wm4.w, patch[4 * j + 3], s);
        }
        oyx = a;
        om = s;
    }

    // ---- software-pipelined tap loop ----
    // iteration k: (A) issue gathers for tap k-1  (B) conv tap k  (C) consume tap k-1
    #pragma unroll 1
    for (int k = 1; k <= KK; ++k) {
        const int kp = k - 1;
        const float* blkp = wsw + kp * TAPBLK;

        // -- phase A: contraction weights (uniform, early) + sampling for tap kp --
        const f4 cw0 = *(const f4*)(blkp + 84);
        const f4 cw1 = *(const f4*)(blkp + 88);
        const f4 cw2 = *(const f4*)(blkp + 92);

        const float m = 1.0f / (1.0f + __expf(-om));

        const float py = hf + (float)(kp / 3 - 1) + oyx.x;
        const float px = wf + (float)(kp % 3 - 1) + oyx.y;
        const float y0f = floorf(py);
        const float x0f = floorf(px);
        const float dy = py - y0f;
        const float dx = px - x0f;
        const int y0 = (int)y0f;
        const int x0 = (int)x0f;

        const f2 dxp = { 1.0f - dx, dx };
        const f2 wT = dxp * (1.0f - dy);   // (w00, w01)
        const f2 wB = dxp * dy;            // (w10, w11)

        const int interior = (y0 >= 0) & (y0 + 1 < HH) & (x0 >= 0) & (x0 + 1 < WW);

        f2 vT0, vB0, vT1, vB1, vT2, vB2;   // gathered 2x2 corners per channel
        if (__all(interior)) {
            const int idx = y0 * WW + x0;
            const float* xp0 = xb + idx;
            const float* xp1 = xp0 + plane;
            const float* xp2 = xp1 + plane;
            vT0 = *(const f2u*)(xp0);  vB0 = *(const f2u*)(xp0 + WW);
            vT1 = *(const f2u*)(xp1);  vB1 = *(const f2u*)(xp1 + WW);
            vT2 = *(const f2u*)(xp2);  vB2 = *(const f2u*)(xp2 + WW);
        } else {
            const bool vy0 = (y0 >= 0)     & (y0 < HH);
            const bool vy1 = (y0 + 1 >= 0) & (y0 + 1 < HH);
            const bool vx0 = (x0 >= 0)     & (x0 < WW);
            const bool vx1 = (x0 + 1 >= 0) & (x0 + 1 < WW);

            const int yc0 = min(max(y0, 0), HH - 1);
            const int yc1 = min(max(y0 + 1, 0), HH - 1);
            const int xc0 = min(max(x0, 0), WW - 1);
            const int xc1 = min(max(x0 + 1, 0), WW - 1);

            const float* xp0 = xb;
            const float* xp1 = xp0 + plane;
            const float* xp2 = xp1 + plane;

            vT0.x = (vy0 & vx0) ? xp0[yc0 * WW + xc0] : 0.0f;
            vT0.y = (vy0 & vx1) ? xp0[yc0 * WW + xc1] : 0.0f;
            vB0.x = (vy1 & vx0) ? xp0[yc1 * WW + xc0] : 0.0f;
            vB0.y = (vy1 & vx1) ? xp0[yc1 * WW + xc1] : 0.0f;
            vT1.x = (vy0 & vx0) ? xp1[yc0 * WW + xc0] : 0.0f;
            vT1.y = (vy0 & vx1) ? xp1[yc0 * WW + xc1] : 0.0f;
            vB1.x = (vy1 & vx0) ? xp1[yc1 * WW + xc0] : 0.0f;
            vB1.y = (vy1 & vx1) ? xp1[yc1 * WW + xc1] : 0.0f;
            vT2.x = (vy0 & vx0) ? xp2[yc0 * WW + xc0] : 0.0f;
            vT2.y = (vy0 & vx1) ? xp2[yc0 * WW + xc1] : 0.0f;
            vB2.x = (vy1 & vx0) ? xp2[yc1 * WW + xc0] : 0.0f;
            vB2.y = (vy1 & vx1) ? xp2[yc1 * WW + xc1] : 0.0f;
        }

        // -- phase B: conv for tap k (independent of in-flight gathers) --
        if (k < KK) {
            const float* blk = wsw + k * TAPBLK;
            f2 a = { b_off[2 * k], b_off[2 * k + 1] };
            float s = b_off[18 + k];
            #pragma unroll
            for (int j = 0; j < 14; ++j) {
                const f4 wq = *(const f4*)(blk + 4 * j);
                const float p0 = patch[2 * j];
                const float p1 = patch[2 * j + 1];
                const f2 w0 = { wq.x, wq.y };
                const f2 w1 = { wq.z, wq.w };
                const f2 pp0 = { p0, p0 };
                const f2 pp1 = { p1, p1 };
                a = __builtin_elementwise_fma(w0, pp0, a);
                a = __builtin_elementwise_fma(w1, pp1, a);
            }
            #pragma unroll
            for (int j = 0; j < 7; ++j) {
                const f4 wm4 = *(const f4*)(blk + 56 + 4 * j);
                s = fmaf(wm4.x, patch[4 * j],     s);
                s = fmaf(wm4.y, patch[4 * j + 1], s);
                s = fmaf(wm4.z, patch[4 * j + 2], s);
                s = fmaf(wm4.w, patch[4 * j + 3], s);
            }
            oyx = a;
            om = s;
        }

        // -- phase C: consume tap kp's gathers (vmcnt wait lands here) --
        {
            f2 s0 = vT0 * wT;
            s0 = __builtin_elementwise_fma(vB0, wB, s0);
            const float val0 = (s0.x + s0.y) * m;
            f2 s1 = vT1 * wT;
            s1 = __builtin_elementwise_fma(vB1, wB, s1);
            const float val1 = (s1.x + s1.y) * m;
            f2 s2 = vT2 * wT;
            s2 = __builtin_elementwise_fma(vB2, wB, s2);
            const float val2 = (s2.x + s2.y) * m;

            const f2 w01_0 = { cw0.x, cw0.y };
            const f2 w01_1 = { cw1.x, cw1.y };
            const f2 w01_2 = { cw2.x, cw2.y };
            const f2 vv0 = { val0, val0 };
            const f2 vv1 = { val1, val1 };
            const f2 vv2 = { val2, val2 };
            acc01 = __builtin_elementwise_fma(w01_0, vv0, acc01);
            acc2 = fmaf(cw0.z, val0, acc2);
            acc01 = __builtin_elementwise_fma(w01_1, vv1, acc01);
            acc2 = fmaf(cw1.z, val1, acc2);
            acc01 = __builtin_elementwise_fma(w01_2, vv2, acc01);
            acc2 = fmaf(cw2.z, val2, acc2);
        }
    }

    const size_t base = (size_t)b * (CIN * plane) + (size_t)h * WW + w;
    out[base]             = acc01.x;
    out[base + plane]     = acc01.y;
    out[base + 2 * plane] = acc2;
}

extern "C" void kernel_launch(void* const* d_in, const int* in_sizes, int n_in,
                              void* d_out, int out_size, void* d_ws, size_t ws_size,
                              hipStream_t stream) {
    const float* x     = (const float*)d_in[0];
    const float* w_off = (const float*)d_in[1];
    const float* b_off = (const float*)d_in[2];
    const float* w_def = (const float*)d_in[3];
    const float* b_def = (const float*)d_in[4];
    float* out = (float*)d_out;
    float* wsw = (float*)d_ws;   // 864 floats of reordered weights

    reorder_weights<<<1, 256, 0, stream>>>(w_off, w_def, wsw);

    dim3 block(256, 1, 1);
    dim3 grid(WW / 256, HH, BN);  // (2, 512, 8)
    deform_fused_kernel<<<grid, block, 0, stream>>>(x, wsw, b_off, b_def, out);
}